// Round 1
// baseline (1953.205 us; speedup 1.0000x reference)
//
#include <hip/hip_runtime.h>
#include <cstdint>

#define T_LEN 4096
#define PAD 2048
#define KG 1408   // 3*256 conv + 640 cond

typedef float f32x4 __attribute__((ext_vector_type(4)));
typedef __bf16 bf16x8 __attribute__((ext_vector_type(8)));

__device__ __forceinline__ void g2l16(const void* g, void* l) {
    __builtin_amdgcn_global_load_lds(
        (__attribute__((address_space(1))) void*)(uintptr_t)g,
        (__attribute__((address_space(3))) void*)(uint32_t)(uintptr_t)l,
        16, 0, 0);
}

// ---------------- setup kernels ----------------

__global__ void zero_kernel(uint4* p) {
    p[(size_t)blockIdx.x * 256 + threadIdx.x] = make_uint4(0u, 0u, 0u, 0u);
}

__global__ void cvt_bf16_kernel(const float* __restrict__ src, __bf16* __restrict__ dst, int n) {
    int idx = blockIdx.x * 256 + threadIdx.x;
    if (idx < n) dst[idx] = (__bf16)src[idx];
}

// started = audio @ w_start + b_start ; write fp32 master + padded bf16 shadow
__global__ void start_kernel(const float* __restrict__ audio, const float* __restrict__ w_start,
                             const float* __restrict__ b_start,
                             float* __restrict__ started_f32, __bf16* __restrict__ started_pad) {
    int r = blockIdx.x, c = threadIdx.x;
    float a0 = audio[r * 4 + 0], a1 = audio[r * 4 + 1], a2 = audio[r * 4 + 2], a3 = audio[r * 4 + 3];
    float s = b_start[c] + a0 * w_start[c] + a1 * w_start[256 + c] + a2 * w_start[512 + c] + a3 * w_start[768 + c];
    started_f32[r * 256 + c] = s;
    int pr = ((r >> 12) << 13) + PAD + (r & 4095);
    started_pad[pr * 256 + c] = (__bf16)s;
}

// Build Wg[i][n'][k] bf16 (n' interleaved by 16: tanh16/sig16 groups), k: 0-767 conv taps, 768-1407 cond
__global__ void transpose_gate(const float* __restrict__ w_in, const float* __restrict__ w_cond,
                               __bf16* __restrict__ Wg) {
    __shared__ float tile[64][65];
    int i = blockIdx.z;
    int k0 = blockIdx.y * 64, n0 = blockIdx.x * 64;
    int tid = threadIdx.x, c = tid & 63, rr = tid >> 6;
    for (int it = 0; it < 16; ++it) {
        int kl = it * 4 + rr;
        int k = k0 + kl;
        int np = n0 + c;
        int phys = ((np >> 4) & 1) * 256 + (np >> 5) * 16 + (np & 15);
        float v;
        if (k < 768) v = w_in[((i * 3 + (k >> 8)) * 256 + (k & 255)) * 512 + phys];
        else         v = w_cond[(i * 640 + (k - 768)) * 512 + phys];
        tile[kl][c] = v;
    }
    __syncthreads();
    for (int it = 0; it < 16; ++it) {
        int nl = it * 4 + rr;
        Wg[(size_t)(i * 512 + n0 + nl) * KG + k0 + c] = (__bf16)tile[c][nl];
    }
}

// generic K x N fp32 -> [N][K] bf16 transpose (tiles of 64x64)
__global__ void transpose_kn(const float* __restrict__ src, __bf16* __restrict__ dst,
                             int K, int N, int srcLS, int dstLS) {
    __shared__ float tile[64][65];
    int i = blockIdx.z;
    int k0 = blockIdx.y * 64, n0 = blockIdx.x * 64;
    int tid = threadIdx.x, c = tid & 63, rr = tid >> 6;
    const float* s = src + (size_t)i * srcLS;
    __bf16* dp = dst + (size_t)i * dstLS;
    for (int it = 0; it < 16; ++it) {
        int kl = it * 4 + rr;
        tile[kl][c] = s[(k0 + kl) * N + n0 + c];
    }
    __syncthreads();
    for (int it = 0; it < 16; ++it) {
        int nl = it * 4 + rr;
        dp[(size_t)(n0 + nl) * K + k0 + c] = (__bf16)tile[c][nl];
    }
}

__global__ void bias_gate_kernel(const float* __restrict__ b_in, const float* __restrict__ b_cond,
                                 float* __restrict__ bias) {
    int idx = blockIdx.x * 256 + threadIdx.x;   // 0..6143
    int i = idx >> 9, np = idx & 511;
    int phys = ((np >> 4) & 1) * 256 + (np >> 5) * 16 + (np & 15);
    bias[idx] = b_in[i * 512 + phys] + b_cond[i * 512 + phys];
}

__global__ void wend_kernel(const float* __restrict__ w_end, float* __restrict__ wendt) {
    int idx = blockIdx.x * 256 + threadIdx.x;   // 0..2047
    int c = idx >> 8, k = idx & 255;
    wendt[idx] = w_end[k * 8 + c];
}

// ---------------- main GEMM kernels ----------------

// fused conv + cond + gate: acts = [3-tap dilated conv of started] + [spect @ w_cond] + bias
// activated = tanh(acts_t) * sigmoid(acts_s)
__global__ __launch_bounds__(256) void gate_kernel(
    const __bf16* __restrict__ started_pad, const __bf16* __restrict__ spect,
    const __bf16* __restrict__ Wg,     // layer base [512][1408]
    const float* __restrict__ bias,    // layer base [512] (interleaved order)
    __bf16* __restrict__ activated, int d) {
    __shared__ __align__(16) __bf16 As[128 * 32];
    __shared__ __align__(16) __bf16 Bs[128 * 32];
    const int tid = threadIdx.x;
    const int m0 = blockIdx.y * 128;
    const int n0 = blockIdx.x * 128;
    const int padbase = ((m0 >> 12) << 13) + PAD + (m0 & 4095);
    const int srow = tid >> 2;
    const int skq = (tid & 3) * 8;
    const int wave = tid >> 6, lane = tid & 63;
    const int wm = (wave >> 1) * 64, wn = (wave & 1) * 64;
    const int quad = lane >> 4, l15 = lane & 15;

    f32x4 acc[4][4];
    for (int i = 0; i < 4; i++)
        for (int j = 0; j < 4; j++) acc[i][j] = f32x4{0.f, 0.f, 0.f, 0.f};

    const __bf16* Bbase = Wg + (n0 + srow) * KG + skq;

    for (int ks = 0; ks < 44; ++ks) {
        int kk = ks * 32;
        const __bf16* gA0;
        int rstride;
        if (kk < 768) {
            int tap = kk >> 8;
            int koff = kk & 255;
            gA0 = started_pad + (padbase + srow + (tap - 1) * d) * 256 + koff + skq;
            rstride = 256;
        } else {
            gA0 = spect + (m0 + srow) * 640 + (kk - 768) + skq;
            rstride = 640;
        }
        g2l16(gA0, &As[srow * 32 + skq]);
        g2l16(gA0 + 64 * rstride, &As[(64 + srow) * 32 + skq]);
        const __bf16* gB0 = Bbase + kk;
        g2l16(gB0, &Bs[srow * 32 + skq]);
        g2l16(gB0 + 64 * KG, &Bs[(64 + srow) * 32 + skq]);
        __syncthreads();
        bf16x8 a[4], b[4];
        for (int mi = 0; mi < 4; mi++) a[mi] = *(const bf16x8*)&As[(wm + mi * 16 + l15) * 32 + quad * 8];
        for (int ni = 0; ni < 4; ni++) b[ni] = *(const bf16x8*)&Bs[(wn + ni * 16 + l15) * 32 + quad * 8];
        for (int mi = 0; mi < 4; mi++)
            for (int ni = 0; ni < 4; ni++)
                acc[mi][ni] = __builtin_amdgcn_mfma_f32_16x16x32_bf16(a[mi], b[ni], acc[mi][ni], 0, 0, 0);
        __syncthreads();
    }

    // epilogue: gating. n' pairs: (ni even = tanh group, ni odd = sigmoid of same 16 channels)
    int chbase = ((n0 + wn) >> 1) + l15;
    for (int nj = 0; nj < 2; ++nj) {
        int colT = wn + nj * 32 + l15;
        float bt = bias[n0 + colT];
        float bs = bias[n0 + colT + 16];
        int ch = chbase + nj * 16;
        for (int mi = 0; mi < 4; ++mi) {
            for (int reg = 0; reg < 4; ++reg) {
                int r = m0 + wm + mi * 16 + quad * 4 + reg;
                float xt = acc[mi][2 * nj][reg] + bt;
                float xs = acc[mi][2 * nj + 1][reg] + bs;
                float th = 2.f / (1.f + __expf(-2.f * xt)) - 1.f;
                float sg = 1.f / (1.f + __expf(-xs));
                activated[r * 256 + ch] = (__bf16)(th * sg);
            }
        }
    }
}

// rs = activated @ w_res + b_res ; started += rs[:, :256] (and refresh bf16 shadow); output += rs[:, 256:]
// last=1: all N=256 cols -> output
__global__ __launch_bounds__(256) void res_kernel(
    const __bf16* __restrict__ activated, const __bf16* __restrict__ Wr,  // [N][256]
    const float* __restrict__ bias, float* __restrict__ started_f32,
    __bf16* __restrict__ started_pad, float* __restrict__ output, int last) {
    __shared__ __align__(16) __bf16 As[128 * 32];
    __shared__ __align__(16) __bf16 Bs[128 * 32];
    const int tid = threadIdx.x;
    const int m0 = blockIdx.y * 128;
    const int n0 = blockIdx.x * 128;
    const int srow = tid >> 2;
    const int skq = (tid & 3) * 8;
    const int wave = tid >> 6, lane = tid & 63;
    const int wm = (wave >> 1) * 64, wn = (wave & 1) * 64;
    const int quad = lane >> 4, l15 = lane & 15;

    f32x4 acc[4][4];
    for (int i = 0; i < 4; i++)
        for (int j = 0; j < 4; j++) acc[i][j] = f32x4{0.f, 0.f, 0.f, 0.f};

    const __bf16* Abase = activated + (m0 + srow) * 256 + skq;
    const __bf16* Bbase = Wr + (n0 + srow) * 256 + skq;

    for (int ks = 0; ks < 8; ++ks) {
        int kk = ks * 32;
        g2l16(Abase + kk, &As[srow * 32 + skq]);
        g2l16(Abase + kk + 64 * 256, &As[(64 + srow) * 32 + skq]);
        g2l16(Bbase + kk, &Bs[srow * 32 + skq]);
        g2l16(Bbase + kk + 64 * 256, &Bs[(64 + srow) * 32 + skq]);
        __syncthreads();
        bf16x8 a[4], b[4];
        for (int mi = 0; mi < 4; mi++) a[mi] = *(const bf16x8*)&As[(wm + mi * 16 + l15) * 32 + quad * 8];
        for (int ni = 0; ni < 4; ni++) b[ni] = *(const bf16x8*)&Bs[(wn + ni * 16 + l15) * 32 + quad * 8];
        for (int mi = 0; mi < 4; mi++)
            for (int ni = 0; ni < 4; ni++)
                acc[mi][ni] = __builtin_amdgcn_mfma_f32_16x16x32_bf16(a[mi], b[ni], acc[mi][ni], 0, 0, 0);
        __syncthreads();
    }

    for (int ni = 0; ni < 4; ++ni) {
        int col = n0 + wn + ni * 16 + l15;
        float bcol = bias[col];
        for (int mi = 0; mi < 4; ++mi) {
            for (int reg = 0; reg < 4; ++reg) {
                int r = m0 + wm + mi * 16 + quad * 4 + reg;
                float val = acc[mi][ni][reg] + bcol;
                if (!last) {
                    if (col < 256) {
                        float f = started_f32[r * 256 + col] + val;
                        started_f32[r * 256 + col] = f;
                        int pr = ((r >> 12) << 13) + PAD + (r & 4095);
                        started_pad[pr * 256 + col] = (__bf16)f;
                    } else {
                        output[r * 256 + (col - 256)] += val;
                    }
                } else {
                    output[r * 256 + col] += val;
                }
            }
        }
    }
}

// out = output @ w_end + b_end  (fp32, N=8)
__global__ void end_kernel(const float* __restrict__ output, const float* __restrict__ wendt,
                           const float* __restrict__ b_end, float* __restrict__ out) {
    int tid = threadIdx.x;
    int r = blockIdx.x * 32 + (tid >> 3);
    int c = tid & 7;
    const float4* po = (const float4*)(output + r * 256);
    const float4* pw = (const float4*)(wendt + c * 256);
    float s = 0.f;
    for (int k = 0; k < 64; ++k) {
        float4 a = po[k], w = pw[k];
        s += a.x * w.x + a.y * w.y + a.z * w.z + a.w * w.w;
    }
    out[r * 8 + c] = s + b_end[c];
}

// ---------------- launch ----------------

extern "C" void kernel_launch(void* const* d_in, const int* in_sizes, int n_in,
                              void* d_out, int out_size, void* d_ws, size_t ws_size,
                              hipStream_t stream) {
    const float* audio      = (const float*)d_in[0];
    const float* spect      = (const float*)d_in[1];
    const float* w_start    = (const float*)d_in[2];
    const float* b_start    = (const float*)d_in[3];
    const float* w_in       = (const float*)d_in[4];
    const float* b_in       = (const float*)d_in[5];
    const float* w_cond     = (const float*)d_in[6];
    const float* b_cond     = (const float*)d_in[7];
    const float* w_res      = (const float*)d_in[8];
    const float* b_res      = (const float*)d_in[9];
    const float* w_res_last = (const float*)d_in[10];
    const float* b_res_last = (const float*)d_in[11];
    const float* w_end      = (const float*)d_in[12];
    const float* b_end      = (const float*)d_in[13];

    char* ws = (char*)d_ws;
    __bf16* started_pad = (__bf16*)ws; ws += 33554432;   // 65536 x 256 bf16 (padded)
    float*  output      = (float*)ws;  ws += 33554432;   // 32768 x 256 f32 (contiguous w/ above for zeroing)
    float*  started_f32 = (float*)ws;  ws += 33554432;   // 32768 x 256 f32
    __bf16* activated   = (__bf16*)ws; ws += 16777216;   // 32768 x 256 bf16
    __bf16* spect_bf    = (__bf16*)ws; ws += 41943040;   // 32768 x 640 bf16
    __bf16* Wg          = (__bf16*)ws; ws += 17301504;   // 12 x 512 x 1408 bf16
    __bf16* Wr          = (__bf16*)ws; ws += 2883584;    // 11 x 512 x 256 bf16
    __bf16* Wrl         = (__bf16*)ws; ws += 131072;     // 256 x 256 bf16
    float*  biasg       = (float*)ws;  ws += 24576;      // 12 x 512 f32
    float*  wendt       = (float*)ws;  ws += 8192;       // 8 x 256 f32

    // zero started_pad + output in one pass (contiguous 64 MiB)
    zero_kernel<<<dim3(16384), 256, 0, stream>>>((uint4*)started_pad);
    cvt_bf16_kernel<<<dim3(81920), 256, 0, stream>>>(spect, spect_bf, 20971520);
    transpose_gate<<<dim3(8, 22, 12), 256, 0, stream>>>(w_in, w_cond, Wg);
    transpose_kn<<<dim3(8, 4, 11), 256, 0, stream>>>(w_res, Wr, 256, 512, 256 * 512, 512 * 256);
    transpose_kn<<<dim3(4, 4, 1), 256, 0, stream>>>(w_res_last, Wrl, 256, 256, 0, 0);
    bias_gate_kernel<<<dim3(24), 256, 0, stream>>>(b_in, b_cond, biasg);
    wend_kernel<<<dim3(8), 256, 0, stream>>>(w_end, wendt);
    start_kernel<<<dim3(32768), 256, 0, stream>>>(audio, w_start, b_start, started_f32, started_pad);

    for (int i = 0; i < 12; ++i) {
        gate_kernel<<<dim3(4, 256), 256, 0, stream>>>(
            started_pad, spect_bf, Wg + (size_t)i * 512 * KG, biasg + i * 512, activated, 1 << i);
        if (i < 11) {
            res_kernel<<<dim3(4, 256), 256, 0, stream>>>(
                activated, Wr + (size_t)i * 512 * 256, b_res + i * 512,
                started_f32, started_pad, output, 0);
        } else {
            res_kernel<<<dim3(2, 256), 256, 0, stream>>>(
                activated, Wrl, b_res_last, started_f32, started_pad, output, 1);
        }
    }
    end_kernel<<<dim3(1024), 256, 0, stream>>>(output, wendt, b_end, (float*)d_out);
}

// Round 2
// 1458.876 us; speedup vs baseline: 1.3388x; 1.3388x over previous
//
#include <hip/hip_runtime.h>
#include <cstdint>

#define PAD 2048
#define KG 1408   // 3*256 conv + 640 cond

typedef float f32x4 __attribute__((ext_vector_type(4)));
typedef __bf16 bf16x8 __attribute__((ext_vector_type(8)));

__device__ __forceinline__ void g2l16(const void* g, void* l) {
    __builtin_amdgcn_global_load_lds(
        (__attribute__((address_space(1))) void*)(uintptr_t)g,
        (__attribute__((address_space(3))) void*)(uint32_t)(uintptr_t)l,
        16, 0, 0);
}

// ---------------- setup kernels ----------------

__global__ void zero_kernel(uint4* p) {
    p[(size_t)blockIdx.x * 256 + threadIdx.x] = make_uint4(0u, 0u, 0u, 0u);
}

__global__ void cvt_bf16_kernel(const float* __restrict__ src, __bf16* __restrict__ dst, int n) {
    int idx = blockIdx.x * 256 + threadIdx.x;
    if (idx < n) dst[idx] = (__bf16)src[idx];
}

// started = audio @ w_start + b_start ; write padded bf16 buffer
__global__ void start_kernel(const float* __restrict__ audio, const float* __restrict__ w_start,
                             const float* __restrict__ b_start, __bf16* __restrict__ started_pad) {
    int r = blockIdx.x, c = threadIdx.x;
    float a0 = audio[r * 4 + 0], a1 = audio[r * 4 + 1], a2 = audio[r * 4 + 2], a3 = audio[r * 4 + 3];
    float s = b_start[c] + a0 * w_start[c] + a1 * w_start[256 + c] + a2 * w_start[512 + c] + a3 * w_start[768 + c];
    int pr = ((r >> 12) << 13) + PAD + (r & 4095);
    started_pad[pr * 256 + c] = (__bf16)s;
}

// Build Wg[i][n'][k] bf16 (n' interleaved by 16: tanh16/sig16 groups), k: 0-767 conv taps, 768-1407 cond
__global__ void transpose_gate(const float* __restrict__ w_in, const float* __restrict__ w_cond,
                               __bf16* __restrict__ Wg) {
    __shared__ float tile[64][65];
    int i = blockIdx.z;
    int k0 = blockIdx.y * 64, n0 = blockIdx.x * 64;
    int tid = threadIdx.x, c = tid & 63, rr = tid >> 6;
    for (int it = 0; it < 16; ++it) {
        int kl = it * 4 + rr;
        int k = k0 + kl;
        int np = n0 + c;
        int phys = ((np >> 4) & 1) * 256 + (np >> 5) * 16 + (np & 15);
        float v;
        if (k < 768) v = w_in[((i * 3 + (k >> 8)) * 256 + (k & 255)) * 512 + phys];
        else         v = w_cond[(i * 640 + (k - 768)) * 512 + phys];
        tile[kl][c] = v;
    }
    __syncthreads();
    for (int it = 0; it < 16; ++it) {
        int nl = it * 4 + rr;
        Wg[(size_t)(i * 512 + n0 + nl) * KG + k0 + c] = (__bf16)tile[c][nl];
    }
}

// generic K x N fp32 -> [N][K] bf16 transpose (tiles of 64x64); grid.x restricted selects n range
__global__ void transpose_kn(const float* __restrict__ src, __bf16* __restrict__ dst,
                             int K, int N, int srcLS, int dstLS) {
    __shared__ float tile[64][65];
    int i = blockIdx.z;
    int k0 = blockIdx.y * 64, n0 = blockIdx.x * 64;
    int tid = threadIdx.x, c = tid & 63, rr = tid >> 6;
    const float* s = src + (size_t)i * srcLS;
    __bf16* dp = dst + (size_t)i * dstLS;
    for (int it = 0; it < 16; ++it) {
        int kl = it * 4 + rr;
        tile[kl][c] = s[(k0 + kl) * N + n0 + c];
    }
    __syncthreads();
    for (int it = 0; it < 16; ++it) {
        int nl = it * 4 + rr;
        dp[(size_t)(n0 + nl) * K + k0 + c] = (__bf16)tile[c][nl];
    }
}

__global__ void bias_gate_kernel(const float* __restrict__ b_in, const float* __restrict__ b_cond,
                                 float* __restrict__ bias) {
    int idx = blockIdx.x * 256 + threadIdx.x;   // 0..6143
    int i = idx >> 9, np = idx & 511;
    int phys = ((np >> 4) & 1) * 256 + (np >> 5) * 16 + (np & 15);
    bias[idx] = b_in[i * 512 + phys] + b_cond[i * 512 + phys];
}

// wfold[i][k][c] = sum_j w_res_skip[i][k][j] * w_end[j][c]   (i=11 uses w_res_last)
__global__ void wfold_kernel(const float* __restrict__ w_res, const float* __restrict__ w_res_last,
                             const float* __restrict__ w_end, float* __restrict__ wfold) {
    int idx = blockIdx.x * 256 + threadIdx.x;   // 0..24575
    int i = idx >> 11, rem = idx & 2047, k = rem >> 3, c = rem & 7;
    float s = 0.f;
    if (i < 11) {
        const float* wr = w_res + (size_t)(i * 256 + k) * 512 + 256;
        for (int j = 0; j < 256; ++j) s += wr[j] * w_end[j * 8 + c];
    } else {
        const float* wr = w_res_last + k * 256;
        for (int j = 0; j < 256; ++j) s += wr[j] * w_end[j * 8 + c];
    }
    wfold[idx] = s;
}

// outconst[c] = b_end[c] + (sum_i b_res_skip[i] + b_res_last) @ w_end
__global__ void outconst_kernel(const float* __restrict__ b_res, const float* __restrict__ b_res_last,
                                const float* __restrict__ b_end, const float* __restrict__ w_end,
                                float* __restrict__ outconst) {
    __shared__ float red[256][8];
    int j = threadIdx.x;
    float bsum = b_res_last[j];
    for (int i = 0; i < 11; ++i) bsum += b_res[i * 512 + 256 + j];
    for (int c = 0; c < 8; ++c) red[j][c] = bsum * w_end[j * 8 + c];
    __syncthreads();
    if (j < 8) {
        float s = b_end[j];
        for (int t = 0; t < 256; ++t) s += red[t][j];
        outconst[j] = s;
    }
}

__global__ void out_init_kernel(const float* __restrict__ outconst, float* __restrict__ out) {
    int idx = blockIdx.x * 256 + threadIdx.x;
    out[idx] = outconst[idx & 7];
}

// ---------------- main GEMM kernels ----------------

// fused conv + cond + gate: acts = [3-tap dilated conv of started] + [spect @ w_cond] + bias
// activated = tanh(acts_t) * sigmoid(acts_s)
__global__ __launch_bounds__(256) void gate_kernel(
    const __bf16* __restrict__ started_pad, const __bf16* __restrict__ spect,
    const __bf16* __restrict__ Wg,     // layer base [512][1408]
    const float* __restrict__ bias,    // layer base [512] (interleaved order)
    __bf16* __restrict__ activated, int d) {
    __shared__ __align__(16) __bf16 As[128 * 32];
    __shared__ __align__(16) __bf16 Bs[128 * 32];
    const int tid = threadIdx.x;
    const int m0 = blockIdx.y * 128;
    const int n0 = blockIdx.x * 128;
    const int padbase = ((m0 >> 12) << 13) + PAD + (m0 & 4095);
    const int srow = tid >> 2;
    const int skq = (tid & 3) * 8;
    const int wave = tid >> 6, lane = tid & 63;
    const int wm = (wave >> 1) * 64, wn = (wave & 1) * 64;
    const int quad = lane >> 4, l15 = lane & 15;

    f32x4 acc[4][4];
    for (int i = 0; i < 4; i++)
        for (int j = 0; j < 4; j++) acc[i][j] = f32x4{0.f, 0.f, 0.f, 0.f};

    const __bf16* Bbase = Wg + (n0 + srow) * KG + skq;

    for (int ks = 0; ks < 44; ++ks) {
        int kk = ks * 32;
        const __bf16* gA0;
        int rstride;
        if (kk < 768) {
            int tap = kk >> 8;
            int koff = kk & 255;
            gA0 = started_pad + (padbase + srow + (tap - 1) * d) * 256 + koff + skq;
            rstride = 256;
        } else {
            gA0 = spect + (m0 + srow) * 640 + (kk - 768) + skq;
            rstride = 640;
        }
        g2l16(gA0, &As[srow * 32 + skq]);
        g2l16(gA0 + 64 * rstride, &As[(64 + srow) * 32 + skq]);
        const __bf16* gB0 = Bbase + kk;
        g2l16(gB0, &Bs[srow * 32 + skq]);
        g2l16(gB0 + 64 * KG, &Bs[(64 + srow) * 32 + skq]);
        __syncthreads();
        bf16x8 a[4], b[4];
        for (int mi = 0; mi < 4; mi++) a[mi] = *(const bf16x8*)&As[(wm + mi * 16 + l15) * 32 + quad * 8];
        for (int ni = 0; ni < 4; ni++) b[ni] = *(const bf16x8*)&Bs[(wn + ni * 16 + l15) * 32 + quad * 8];
        for (int mi = 0; mi < 4; mi++)
            for (int ni = 0; ni < 4; ni++)
                acc[mi][ni] = __builtin_amdgcn_mfma_f32_16x16x32_bf16(a[mi], b[ni], acc[mi][ni], 0, 0, 0);
        __syncthreads();
    }

    // epilogue: gating. n' pairs: (ni even = tanh group, ni odd = sigmoid of same 16 channels)
    int chbase = ((n0 + wn) >> 1) + l15;
    for (int nj = 0; nj < 2; ++nj) {
        int colT = wn + nj * 32 + l15;
        float bt = bias[n0 + colT];
        float bs = bias[n0 + colT + 16];
        int ch = chbase + nj * 16;
        for (int mi = 0; mi < 4; ++mi) {
            for (int reg = 0; reg < 4; ++reg) {
                int r = m0 + wm + mi * 16 + quad * 4 + reg;
                float xt = acc[mi][2 * nj][reg] + bt;
                float xs = acc[mi][2 * nj + 1][reg] + bs;
                float th = 2.f / (1.f + __expf(-2.f * xt)) - 1.f;
                float sg = 1.f / (1.f + __expf(-xs));
                activated[r * 256 + ch] = (__bf16)(th * sg);
            }
        }
    }
}

// rs_res = activated @ Wr + b_res ; started_pad += rs_res (bf16 RMW)
// blocks with n0==0 additionally accumulate out += activated @ wfold (float4 RMW, unique rows)
__global__ __launch_bounds__(256) void res_kernel(
    const __bf16* __restrict__ activated, const __bf16* __restrict__ Wr,  // [256][256]
    const float* __restrict__ b_res,      // layer base (first 256 cols used)
    const float* __restrict__ wfold,      // layer base [256][8]
    __bf16* __restrict__ started_pad, float* __restrict__ out) {
    __shared__ __align__(16) __bf16 As[128 * 32];
    __shared__ __align__(16) __bf16 Bs[128 * 32];
    __shared__ __align__(16) float Wf[2048];   // 256 x 8
    const int tid = threadIdx.x;
    const int m0 = blockIdx.y * 128;
    const int n0 = blockIdx.x * 128;
    const int srow = tid >> 2;
    const int skq = (tid & 3) * 8;
    const int wave = tid >> 6, lane = tid & 63;
    const int wm = (wave >> 1) * 64, wn = (wave & 1) * 64;
    const int quad = lane >> 4, l15 = lane & 15;
    const bool doOut = (blockIdx.x == 0);
    const int row2 = tid >> 1, half = tid & 1;

    if (doOut) {
        float4* wf4 = (float4*)Wf;
        const float4* src4 = (const float4*)wfold;
        wf4[tid] = src4[tid];
        wf4[256 + tid] = src4[256 + tid];
    }

    f32x4 acc[4][4];
    for (int i = 0; i < 4; i++)
        for (int j = 0; j < 4; j++) acc[i][j] = f32x4{0.f, 0.f, 0.f, 0.f};
    float ox = 0.f, oy = 0.f, oz = 0.f, ow = 0.f;

    const __bf16* Abase = activated + (m0 + srow) * 256 + skq;
    const __bf16* Bbase = Wr + (n0 + srow) * 256 + skq;

    for (int ks = 0; ks < 8; ++ks) {
        int kk = ks * 32;
        g2l16(Abase + kk, &As[srow * 32 + skq]);
        g2l16(Abase + kk + 64 * 256, &As[(64 + srow) * 32 + skq]);
        g2l16(Bbase + kk, &Bs[srow * 32 + skq]);
        g2l16(Bbase + kk + 64 * 256, &Bs[(64 + srow) * 32 + skq]);
        __syncthreads();
        bf16x8 a[4], b[4];
        for (int mi = 0; mi < 4; mi++) a[mi] = *(const bf16x8*)&As[(wm + mi * 16 + l15) * 32 + quad * 8];
        for (int ni = 0; ni < 4; ni++) b[ni] = *(const bf16x8*)&Bs[(wn + ni * 16 + l15) * 32 + quad * 8];
        for (int mi = 0; mi < 4; mi++)
            for (int ni = 0; ni < 4; ni++)
                acc[mi][ni] = __builtin_amdgcn_mfma_f32_16x16x32_bf16(a[mi], b[ni], acc[mi][ni], 0, 0, 0);
        if (doOut) {
            const bf16x8* ap = (const bf16x8*)&As[row2 * 32];
            const float4* wf = (const float4*)Wf;
            for (int c8 = 0; c8 < 4; ++c8) {
                bf16x8 av = ap[c8];
                int kb = (kk + c8 * 8) * 2 + half;
                for (int e = 0; e < 8; ++e) {
                    float a = (float)av[e];
                    float4 w = wf[kb + e * 2];
                    ox += a * w.x; oy += a * w.y; oz += a * w.z; ow += a * w.w;
                }
            }
        }
        __syncthreads();
    }

    for (int ni = 0; ni < 4; ++ni) {
        int col = n0 + wn + ni * 16 + l15;
        float bcol = b_res[col];
        for (int mi = 0; mi < 4; ++mi) {
            for (int reg = 0; reg < 4; ++reg) {
                int r = m0 + wm + mi * 16 + quad * 4 + reg;
                int pr = ((r >> 12) << 13) + PAD + (r & 4095);
                int idx = pr * 256 + col;
                float f = (float)started_pad[idx] + acc[mi][ni][reg] + bcol;
                started_pad[idx] = (__bf16)f;
            }
        }
    }
    if (doOut) {
        int r = m0 + row2;
        float4* op = (float4*)&out[r * 8 + half * 4];
        float4 o = *op;
        o.x += ox; o.y += oy; o.z += oz; o.w += ow;
        *op = o;
    }
}

// last layer: out += activated @ wfold[11]  (no res half)
__global__ __launch_bounds__(256) void outacc_kernel(
    const __bf16* __restrict__ activated, const float* __restrict__ wfold,
    float* __restrict__ out) {
    __shared__ __align__(16) float Wf[2048];
    int tid = threadIdx.x;
    ((float4*)Wf)[tid] = ((const float4*)wfold)[tid];
    ((float4*)Wf)[256 + tid] = ((const float4*)wfold)[256 + tid];
    __syncthreads();
    int row2 = tid >> 1, half = tid & 1;
    int r = blockIdx.x * 128 + row2;
    const bf16x8* ap = (const bf16x8*)(activated + r * 256);
    const float4* wf = (const float4*)Wf;
    float ox = 0.f, oy = 0.f, oz = 0.f, ow = 0.f;
    for (int c8 = 0; c8 < 32; ++c8) {
        bf16x8 av = ap[c8];
        for (int e = 0; e < 8; ++e) {
            float a = (float)av[e];
            float4 w = wf[(c8 * 8 + e) * 2 + half];
            ox += a * w.x; oy += a * w.y; oz += a * w.z; ow += a * w.w;
        }
    }
    float4* op = (float4*)&out[r * 8 + half * 4];
    float4 o = *op;
    o.x += ox; o.y += oy; o.z += oz; o.w += ow;
    *op = o;
}

// ---------------- launch ----------------

extern "C" void kernel_launch(void* const* d_in, const int* in_sizes, int n_in,
                              void* d_out, int out_size, void* d_ws, size_t ws_size,
                              hipStream_t stream) {
    const float* audio      = (const float*)d_in[0];
    const float* spect      = (const float*)d_in[1];
    const float* w_start    = (const float*)d_in[2];
    const float* b_start    = (const float*)d_in[3];
    const float* w_in       = (const float*)d_in[4];
    const float* b_in       = (const float*)d_in[5];
    const float* w_cond     = (const float*)d_in[6];
    const float* b_cond     = (const float*)d_in[7];
    const float* w_res      = (const float*)d_in[8];
    const float* b_res      = (const float*)d_in[9];
    const float* w_res_last = (const float*)d_in[10];
    const float* b_res_last = (const float*)d_in[11];
    const float* w_end      = (const float*)d_in[12];
    const float* b_end      = (const float*)d_in[13];
    float* out = (float*)d_out;

    char* ws = (char*)d_ws;
    __bf16* started_pad = (__bf16*)ws; ws += 33554432;   // 65536 x 256 bf16 (padded)
    __bf16* activated   = (__bf16*)ws; ws += 16777216;   // 32768 x 256 bf16
    __bf16* spect_bf    = (__bf16*)ws; ws += 41943040;   // 32768 x 640 bf16
    __bf16* Wg          = (__bf16*)ws; ws += 17301504;   // 12 x 512 x 1408 bf16
    __bf16* Wr          = (__bf16*)ws; ws += 1441792;    // 11 x 256 x 256 bf16 (res half, [n][k])
    float*  wfold       = (float*)ws;  ws += 98304;      // 12 x 256 x 8 f32
    float*  biasg       = (float*)ws;  ws += 24576;      // 12 x 512 f32
    float*  outconst    = (float*)ws;  ws += 256;        // 8 f32

    zero_kernel<<<dim3(8192), 256, 0, stream>>>((uint4*)started_pad);
    cvt_bf16_kernel<<<dim3(81920), 256, 0, stream>>>(spect, spect_bf, 20971520);
    transpose_gate<<<dim3(8, 22, 12), 256, 0, stream>>>(w_in, w_cond, Wg);
    transpose_kn<<<dim3(4, 4, 11), 256, 0, stream>>>(w_res, Wr, 256, 512, 256 * 512, 256 * 256);
    bias_gate_kernel<<<dim3(24), 256, 0, stream>>>(b_in, b_cond, biasg);
    wfold_kernel<<<dim3(96), 256, 0, stream>>>(w_res, w_res_last, w_end, wfold);
    outconst_kernel<<<dim3(1), 256, 0, stream>>>(b_res, b_res_last, b_end, w_end, outconst);
    out_init_kernel<<<dim3(1024), 256, 0, stream>>>(outconst, out);
    start_kernel<<<dim3(32768), 256, 0, stream>>>(audio, w_start, b_start, started_pad);

    for (int i = 0; i < 12; ++i) {
        gate_kernel<<<dim3(4, 256), 256, 0, stream>>>(
            started_pad, spect_bf, Wg + (size_t)i * 512 * KG, biasg + i * 512, activated, 1 << i);
        if (i < 11) {
            res_kernel<<<dim3(2, 256), 256, 0, stream>>>(
                activated, Wr + (size_t)i * 256 * 256, b_res + i * 512,
                wfold + i * 2048, started_pad, out);
        } else {
            outacc_kernel<<<dim3(256), 256, 0, stream>>>(activated, wfold + 11 * 2048, out);
        }
    }
}

// Round 3
// 1454.134 us; speedup vs baseline: 1.3432x; 1.0033x over previous
//
#include <hip/hip_runtime.h>
#include <cstdint>

#define PAD 2048
#define KG 1408   // 3*256 conv + 640 cond

typedef float f32x4 __attribute__((ext_vector_type(4)));
typedef __bf16 bf16x8 __attribute__((ext_vector_type(8)));

// ---------------- setup kernels ----------------

__global__ void zero_kernel(uint4* p) {
    p[(size_t)blockIdx.x * 256 + threadIdx.x] = make_uint4(0u, 0u, 0u, 0u);
}

__global__ void cvt_bf16_kernel(const float* __restrict__ src, __bf16* __restrict__ dst, int n) {
    int idx = blockIdx.x * 256 + threadIdx.x;
    if (idx < n) dst[idx] = (__bf16)src[idx];
}

// started = audio @ w_start + b_start ; write padded bf16 buffer
__global__ void start_kernel(const float* __restrict__ audio, const float* __restrict__ w_start,
                             const float* __restrict__ b_start, __bf16* __restrict__ started_pad) {
    int r = blockIdx.x, c = threadIdx.x;
    float a0 = audio[r * 4 + 0], a1 = audio[r * 4 + 1], a2 = audio[r * 4 + 2], a3 = audio[r * 4 + 3];
    float s = b_start[c] + a0 * w_start[c] + a1 * w_start[256 + c] + a2 * w_start[512 + c] + a3 * w_start[768 + c];
    int pr = ((r >> 12) << 13) + PAD + (r & 4095);
    started_pad[pr * 256 + c] = (__bf16)s;
}

// Build Wg[i][n'][k] bf16 (n' interleaved by 16: tanh16/sig16 groups), k: 0-767 conv taps, 768-1407 cond
__global__ void transpose_gate(const float* __restrict__ w_in, const float* __restrict__ w_cond,
                               __bf16* __restrict__ Wg) {
    __shared__ float tile[64][65];
    int i = blockIdx.z;
    int k0 = blockIdx.y * 64, n0 = blockIdx.x * 64;
    int tid = threadIdx.x, c = tid & 63, rr = tid >> 6;
    for (int it = 0; it < 16; ++it) {
        int kl = it * 4 + rr;
        int k = k0 + kl;
        int np = n0 + c;
        int phys = ((np >> 4) & 1) * 256 + (np >> 5) * 16 + (np & 15);
        float v;
        if (k < 768) v = w_in[((i * 3 + (k >> 8)) * 256 + (k & 255)) * 512 + phys];
        else         v = w_cond[(i * 640 + (k - 768)) * 512 + phys];
        tile[kl][c] = v;
    }
    __syncthreads();
    for (int it = 0; it < 16; ++it) {
        int nl = it * 4 + rr;
        Wg[(size_t)(i * 512 + n0 + nl) * KG + k0 + c] = (__bf16)tile[c][nl];
    }
}

// generic K x N fp32 -> [N][K] bf16 transpose (tiles of 64x64)
__global__ void transpose_kn(const float* __restrict__ src, __bf16* __restrict__ dst,
                             int K, int N, int srcLS, int dstLS) {
    __shared__ float tile[64][65];
    int i = blockIdx.z;
    int k0 = blockIdx.y * 64, n0 = blockIdx.x * 64;
    int tid = threadIdx.x, c = tid & 63, rr = tid >> 6;
    const float* s = src + (size_t)i * srcLS;
    __bf16* dp = dst + (size_t)i * dstLS;
    for (int it = 0; it < 16; ++it) {
        int kl = it * 4 + rr;
        tile[kl][c] = s[(k0 + kl) * N + n0 + c];
    }
    __syncthreads();
    for (int it = 0; it < 16; ++it) {
        int nl = it * 4 + rr;
        dp[(size_t)(n0 + nl) * K + k0 + c] = (__bf16)tile[c][nl];
    }
}

__global__ void bias_gate_kernel(const float* __restrict__ b_in, const float* __restrict__ b_cond,
                                 float* __restrict__ bias) {
    int idx = blockIdx.x * 256 + threadIdx.x;   // 0..6143
    int i = idx >> 9, np = idx & 511;
    int phys = ((np >> 4) & 1) * 256 + (np >> 5) * 16 + (np & 15);
    bias[idx] = b_in[i * 512 + phys] + b_cond[i * 512 + phys];
}

// wfold[i][k][c] = sum_j w_res_skip[i][k][j] * w_end[j][c]   (i=11 uses w_res_last)
__global__ void wfold_kernel(const float* __restrict__ w_res, const float* __restrict__ w_res_last,
                             const float* __restrict__ w_end, float* __restrict__ wfold) {
    int idx = blockIdx.x * 256 + threadIdx.x;   // 0..24575
    int i = idx >> 11, rem = idx & 2047, k = rem >> 3, c = rem & 7;
    float s = 0.f;
    if (i < 11) {
        const float* wr = w_res + (size_t)(i * 256 + k) * 512 + 256;
        for (int j = 0; j < 256; ++j) s += wr[j] * w_end[j * 8 + c];
    } else {
        const float* wr = w_res_last + k * 256;
        for (int j = 0; j < 256; ++j) s += wr[j] * w_end[j * 8 + c];
    }
    wfold[idx] = s;
}

// outconst[c] = b_end[c] + (sum_i b_res_skip[i] + b_res_last) @ w_end
__global__ void outconst_kernel(const float* __restrict__ b_res, const float* __restrict__ b_res_last,
                                const float* __restrict__ b_end, const float* __restrict__ w_end,
                                float* __restrict__ outconst) {
    __shared__ float red[256][8];
    int j = threadIdx.x;
    float bsum = b_res_last[j];
    for (int i = 0; i < 11; ++i) bsum += b_res[i * 512 + 256 + j];
    for (int c = 0; c < 8; ++c) red[j][c] = bsum * w_end[j * 8 + c];
    __syncthreads();
    if (j < 8) {
        float s = b_end[j];
        for (int t = 0; t < 256; ++t) s += red[t][j];
        outconst[j] = s;
    }
}

__global__ void out_init_kernel(const float* __restrict__ outconst, float* __restrict__ out) {
    int idx = blockIdx.x * 256 + threadIdx.x;
    out[idx] = outconst[idx & 7];
}

// ---------------- main GEMM kernels ----------------

// fused conv + cond + gate, with global->reg->LDS 2-stage pipeline:
// loads for tile k+1 are issued right after the LDS write of tile k, so the
// mandatory vmcnt wait lands one full compute stage after issue (latency hidden).
__global__ __launch_bounds__(256) void gate_kernel(
    const __bf16* __restrict__ started_pad, const __bf16* __restrict__ spect,
    const __bf16* __restrict__ Wg,     // layer base [512][1408]
    const float* __restrict__ bias,    // layer base [512] (interleaved order)
    __bf16* __restrict__ activated, int d) {
    __shared__ __align__(16) __bf16 As[128 * 32];
    __shared__ __align__(16) __bf16 Bs[128 * 32];
    const int tid = threadIdx.x;
    const int m0 = blockIdx.y * 128;
    const int n0 = blockIdx.x * 128;
    const int padbase = ((m0 >> 12) << 13) + PAD + (m0 & 4095);
    const int srow = tid >> 2;
    const int skq = (tid & 3) * 8;
    const int wave = tid >> 6, lane = tid & 63;
    const int wm = (wave >> 1) * 64, wn = (wave & 1) * 64;
    const int quad = lane >> 4, l15 = lane & 15;

    f32x4 acc[4][4];
    for (int i = 0; i < 4; i++)
        for (int j = 0; j < 4; j++) acc[i][j] = f32x4{0.f, 0.f, 0.f, 0.f};

    const __bf16* Bbase = Wg + (n0 + srow) * KG + skq;

    // prefetch tile 0 into registers
    bf16x8 rA0, rA1, rB0, rB1;
    {
        const __bf16* gA0 = started_pad + (padbase + srow - d) * 256 + skq;
        rA0 = *(const bf16x8*)gA0;
        rA1 = *(const bf16x8*)(gA0 + 64 * 256);
        rB0 = *(const bf16x8*)Bbase;
        rB1 = *(const bf16x8*)(Bbase + 64 * KG);
    }

    for (int ks = 0; ks < 44; ++ks) {
        __syncthreads();   // prev iteration's ds_reads complete
        *(bf16x8*)&As[srow * 32 + skq] = rA0;
        *(bf16x8*)&As[(64 + srow) * 32 + skq] = rA1;
        *(bf16x8*)&Bs[srow * 32 + skq] = rB0;
        *(bf16x8*)&Bs[(64 + srow) * 32 + skq] = rB1;
        if (ks + 1 < 44) {
            int kk = (ks + 1) * 32;
            const __bf16* gA0;
            int rstride;
            if (kk < 768) {
                int tap = kk >> 8;
                int koff = kk & 255;
                gA0 = started_pad + (padbase + srow + (tap - 1) * d) * 256 + koff + skq;
                rstride = 256;
            } else {
                gA0 = spect + (m0 + srow) * 640 + (kk - 768) + skq;
                rstride = 640;
            }
            rA0 = *(const bf16x8*)gA0;
            rA1 = *(const bf16x8*)(gA0 + 64 * rstride);
            const __bf16* gB0 = Bbase + kk;
            rB0 = *(const bf16x8*)gB0;
            rB1 = *(const bf16x8*)(gB0 + 64 * KG);
        }
        __syncthreads();   // LDS writes visible
        bf16x8 a[4], b[4];
        for (int mi = 0; mi < 4; mi++) a[mi] = *(const bf16x8*)&As[(wm + mi * 16 + l15) * 32 + quad * 8];
        for (int ni = 0; ni < 4; ni++) b[ni] = *(const bf16x8*)&Bs[(wn + ni * 16 + l15) * 32 + quad * 8];
        for (int mi = 0; mi < 4; mi++)
            for (int ni = 0; ni < 4; ni++)
                acc[mi][ni] = __builtin_amdgcn_mfma_f32_16x16x32_bf16(a[mi], b[ni], acc[mi][ni], 0, 0, 0);
    }

    // epilogue: gating. n' pairs: (ni even = tanh group, ni odd = sigmoid of same 16 channels)
    int chbase = ((n0 + wn) >> 1) + l15;
    for (int nj = 0; nj < 2; ++nj) {
        int colT = wn + nj * 32 + l15;
        float bt = bias[n0 + colT];
        float bs = bias[n0 + colT + 16];
        int ch = chbase + nj * 16;
        for (int mi = 0; mi < 4; ++mi) {
            for (int reg = 0; reg < 4; ++reg) {
                int r = m0 + wm + mi * 16 + quad * 4 + reg;
                float xt = acc[mi][2 * nj][reg] + bt;
                float xs = acc[mi][2 * nj + 1][reg] + bs;
                float th = 2.f / (1.f + __expf(-2.f * xt)) - 1.f;
                float sg = 1.f / (1.f + __expf(-xs));
                activated[r * 256 + ch] = (__bf16)(th * sg);
            }
        }
    }
}

// rs_res = activated @ Wr + b_res ; started_pad += rs_res (bf16 RMW)
// blocks with n0==0 additionally accumulate out += activated @ wfold (float4 RMW, unique rows)
__global__ __launch_bounds__(256) void res_kernel(
    const __bf16* __restrict__ activated, const __bf16* __restrict__ Wr,  // [256][256]
    const float* __restrict__ b_res,      // layer base (first 256 cols used)
    const float* __restrict__ wfold,      // layer base [256][8]
    __bf16* __restrict__ started_pad, float* __restrict__ out) {
    __shared__ __align__(16) __bf16 As[128 * 32];
    __shared__ __align__(16) __bf16 Bs[128 * 32];
    __shared__ __align__(16) float Wf[2048];   // 256 x 8
    const int tid = threadIdx.x;
    const int m0 = blockIdx.y * 128;
    const int n0 = blockIdx.x * 128;
    const int srow = tid >> 2;
    const int skq = (tid & 3) * 8;
    const int wave = tid >> 6, lane = tid & 63;
    const int wm = (wave >> 1) * 64, wn = (wave & 1) * 64;
    const int quad = lane >> 4, l15 = lane & 15;
    const bool doOut = (blockIdx.x == 0);
    const int row2 = tid >> 1, half = tid & 1;

    if (doOut) {
        float4* wf4 = (float4*)Wf;
        const float4* src4 = (const float4*)wfold;
        wf4[tid] = src4[tid];
        wf4[256 + tid] = src4[256 + tid];
    }

    f32x4 acc[4][4];
    for (int i = 0; i < 4; i++)
        for (int j = 0; j < 4; j++) acc[i][j] = f32x4{0.f, 0.f, 0.f, 0.f};
    float ox = 0.f, oy = 0.f, oz = 0.f, ow = 0.f;

    const __bf16* Abase = activated + (m0 + srow) * 256 + skq;
    const __bf16* Bbase = Wr + (n0 + srow) * 256 + skq;

    bf16x8 rA0, rA1, rB0, rB1;
    rA0 = *(const bf16x8*)Abase;
    rA1 = *(const bf16x8*)(Abase + 64 * 256);
    rB0 = *(const bf16x8*)Bbase;
    rB1 = *(const bf16x8*)(Bbase + 64 * 256);

    for (int ks = 0; ks < 8; ++ks) {
        __syncthreads();
        *(bf16x8*)&As[srow * 32 + skq] = rA0;
        *(bf16x8*)&As[(64 + srow) * 32 + skq] = rA1;
        *(bf16x8*)&Bs[srow * 32 + skq] = rB0;
        *(bf16x8*)&Bs[(64 + srow) * 32 + skq] = rB1;
        if (ks + 1 < 8) {
            int kk = (ks + 1) * 32;
            rA0 = *(const bf16x8*)(Abase + kk);
            rA1 = *(const bf16x8*)(Abase + kk + 64 * 256);
            rB0 = *(const bf16x8*)(Bbase + kk);
            rB1 = *(const bf16x8*)(Bbase + kk + 64 * 256);
        }
        __syncthreads();
        bf16x8 a[4], b[4];
        for (int mi = 0; mi < 4; mi++) a[mi] = *(const bf16x8*)&As[(wm + mi * 16 + l15) * 32 + quad * 8];
        for (int ni = 0; ni < 4; ni++) b[ni] = *(const bf16x8*)&Bs[(wn + ni * 16 + l15) * 32 + quad * 8];
        for (int mi = 0; mi < 4; mi++)
            for (int ni = 0; ni < 4; ni++)
                acc[mi][ni] = __builtin_amdgcn_mfma_f32_16x16x32_bf16(a[mi], b[ni], acc[mi][ni], 0, 0, 0);
        if (doOut) {
            int kk = ks * 32;
            const bf16x8* ap = (const bf16x8*)&As[row2 * 32];
            const float4* wf = (const float4*)Wf;
            for (int c8 = 0; c8 < 4; ++c8) {
                bf16x8 av = ap[c8];
                int kb = (kk + c8 * 8) * 2 + half;
                for (int e = 0; e < 8; ++e) {
                    float a = (float)av[e];
                    float4 w = wf[kb + e * 2];
                    ox += a * w.x; oy += a * w.y; oz += a * w.z; ow += a * w.w;
                }
            }
        }
    }

    for (int ni = 0; ni < 4; ++ni) {
        int col = n0 + wn + ni * 16 + l15;
        float bcol = b_res[col];
        for (int mi = 0; mi < 4; ++mi) {
            for (int reg = 0; reg < 4; ++reg) {
                int r = m0 + wm + mi * 16 + quad * 4 + reg;
                int pr = ((r >> 12) << 13) + PAD + (r & 4095);
                int idx = pr * 256 + col;
                float f = (float)started_pad[idx] + acc[mi][ni][reg] + bcol;
                started_pad[idx] = (__bf16)f;
            }
        }
    }
    if (doOut) {
        int r = m0 + row2;
        float4* op = (float4*)&out[r * 8 + half * 4];
        float4 o = *op;
        o.x += ox; o.y += oy; o.z += oz; o.w += ow;
        *op = o;
    }
}

// last layer: out += activated @ wfold[11]  (no res half)
__global__ __launch_bounds__(256) void outacc_kernel(
    const __bf16* __restrict__ activated, const float* __restrict__ wfold,
    float* __restrict__ out) {
    __shared__ __align__(16) float Wf[2048];
    int tid = threadIdx.x;
    ((float4*)Wf)[tid] = ((const float4*)wfold)[tid];
    ((float4*)Wf)[256 + tid] = ((const float4*)wfold)[256 + tid];
    __syncthreads();
    int row2 = tid >> 1, half = tid & 1;
    int r = blockIdx.x * 128 + row2;
    const bf16x8* ap = (const bf16x8*)(activated + r * 256);
    const float4* wf = (const float4*)Wf;
    float ox = 0.f, oy = 0.f, oz = 0.f, ow = 0.f;
    for (int c8 = 0; c8 < 32; ++c8) {
        bf16x8 av = ap[c8];
        for (int e = 0; e < 8; ++e) {
            float a = (float)av[e];
            float4 w = wf[(c8 * 8 + e) * 2 + half];
            ox += a * w.x; oy += a * w.y; oz += a * w.z; ow += a * w.w;
        }
    }
    float4* op = (float4*)&out[r * 8 + half * 4];
    float4 o = *op;
    o.x += ox; o.y += oy; o.z += oz; o.w += ow;
    *op = o;
}

// ---------------- launch ----------------

extern "C" void kernel_launch(void* const* d_in, const int* in_sizes, int n_in,
                              void* d_out, int out_size, void* d_ws, size_t ws_size,
                              hipStream_t stream) {
    const float* audio      = (const float*)d_in[0];
    const float* spect      = (const float*)d_in[1];
    const float* w_start    = (const float*)d_in[2];
    const float* b_start    = (const float*)d_in[3];
    const float* w_in       = (const float*)d_in[4];
    const float* b_in       = (const float*)d_in[5];
    const float* w_cond     = (const float*)d_in[6];
    const float* b_cond     = (const float*)d_in[7];
    const float* w_res      = (const float*)d_in[8];
    const float* b_res      = (const float*)d_in[9];
    const float* w_res_last = (const float*)d_in[10];
    const float* b_res_last = (const float*)d_in[11];
    const float* w_end      = (const float*)d_in[12];
    const float* b_end      = (const float*)d_in[13];
    float* out = (float*)d_out;

    char* ws = (char*)d_ws;
    __bf16* started_pad = (__bf16*)ws; ws += 33554432;   // 65536 x 256 bf16 (padded)
    __bf16* activated   = (__bf16*)ws; ws += 16777216;   // 32768 x 256 bf16
    __bf16* spect_bf    = (__bf16*)ws; ws += 41943040;   // 32768 x 640 bf16
    __bf16* Wg          = (__bf16*)ws; ws += 17301504;   // 12 x 512 x 1408 bf16
    __bf16* Wr          = (__bf16*)ws; ws += 1441792;    // 11 x 256 x 256 bf16 (res half, [n][k])
    float*  wfold       = (float*)ws;  ws += 98304;      // 12 x 256 x 8 f32
    float*  biasg       = (float*)ws;  ws += 24576;      // 12 x 512 f32
    float*  outconst    = (float*)ws;  ws += 256;        // 8 f32

    zero_kernel<<<dim3(8192), 256, 0, stream>>>((uint4*)started_pad);
    cvt_bf16_kernel<<<dim3(81920), 256, 0, stream>>>(spect, spect_bf, 20971520);
    transpose_gate<<<dim3(8, 22, 12), 256, 0, stream>>>(w_in, w_cond, Wg);
    transpose_kn<<<dim3(4, 4, 11), 256, 0, stream>>>(w_res, Wr, 256, 512, 256 * 512, 256 * 256);
    bias_gate_kernel<<<dim3(24), 256, 0, stream>>>(b_in, b_cond, biasg);
    wfold_kernel<<<dim3(96), 256, 0, stream>>>(w_res, w_res_last, w_end, wfold);
    outconst_kernel<<<dim3(1), 256, 0, stream>>>(b_res, b_res_last, b_end, w_end, outconst);
    out_init_kernel<<<dim3(1024), 256, 0, stream>>>(outconst, out);
    start_kernel<<<dim3(32768), 256, 0, stream>>>(audio, w_start, b_start, started_pad);

    for (int i = 0; i < 12; ++i) {
        gate_kernel<<<dim3(4, 256), 256, 0, stream>>>(
            started_pad, spect_bf, Wg + (size_t)i * 512 * KG, biasg + i * 512, activated, 1 << i);
        if (i < 11) {
            res_kernel<<<dim3(2, 256), 256, 0, stream>>>(
                activated, Wr + (size_t)i * 256 * 256, b_res + i * 512,
                wfold + i * 2048, started_pad, out);
        } else {
            outacc_kernel<<<dim3(256), 256, 0, stream>>>(activated, wfold + 11 * 2048, out);
        }
    }
}

// Round 4
// 1328.569 us; speedup vs baseline: 1.4702x; 1.0945x over previous
//
#include <hip/hip_runtime.h>
#include <cstdint>

#define PAD 2048
#define KG 1408   // 3*256 conv + 640 cond

typedef float f32x4 __attribute__((ext_vector_type(4)));
typedef __bf16 bf16x8 __attribute__((ext_vector_type(8)));

__device__ __forceinline__ void g2l16(const void* g, void* l) {
    __builtin_amdgcn_global_load_lds(
        (__attribute__((address_space(1))) void*)(uintptr_t)g,
        (__attribute__((address_space(3))) void*)(uint32_t)(uintptr_t)l,
        16, 0, 0);
}

// ---------------- setup kernels ----------------

__global__ void zero_kernel(uint4* p) {
    p[(size_t)blockIdx.x * 256 + threadIdx.x] = make_uint4(0u, 0u, 0u, 0u);
}

__global__ void cvt_bf16_kernel(const float* __restrict__ src, __bf16* __restrict__ dst, int n) {
    int idx = blockIdx.x * 256 + threadIdx.x;
    if (idx < n) dst[idx] = (__bf16)src[idx];
}

// started = audio @ w_start + b_start ; write padded bf16 buffer
__global__ void start_kernel(const float* __restrict__ audio, const float* __restrict__ w_start,
                             const float* __restrict__ b_start, __bf16* __restrict__ started_pad) {
    int r = blockIdx.x, c = threadIdx.x;
    float a0 = audio[r * 4 + 0], a1 = audio[r * 4 + 1], a2 = audio[r * 4 + 2], a3 = audio[r * 4 + 3];
    float s = b_start[c] + a0 * w_start[c] + a1 * w_start[256 + c] + a2 * w_start[512 + c] + a3 * w_start[768 + c];
    int pr = ((r >> 12) << 13) + PAD + (r & 4095);
    started_pad[pr * 256 + c] = (__bf16)s;
}

// Build Wg[i][n'][k] bf16 (n' interleaved by 16: tanh16/sig16 groups), k: 0-767 conv taps, 768-1407 cond
__global__ void transpose_gate(const float* __restrict__ w_in, const float* __restrict__ w_cond,
                               __bf16* __restrict__ Wg) {
    __shared__ float tile[64][65];
    int i = blockIdx.z;
    int k0 = blockIdx.y * 64, n0 = blockIdx.x * 64;
    int tid = threadIdx.x, c = tid & 63, rr = tid >> 6;
    for (int it = 0; it < 16; ++it) {
        int kl = it * 4 + rr;
        int k = k0 + kl;
        int np = n0 + c;
        int phys = ((np >> 4) & 1) * 256 + (np >> 5) * 16 + (np & 15);
        float v;
        if (k < 768) v = w_in[((i * 3 + (k >> 8)) * 256 + (k & 255)) * 512 + phys];
        else         v = w_cond[(i * 640 + (k - 768)) * 512 + phys];
        tile[kl][c] = v;
    }
    __syncthreads();
    for (int it = 0; it < 16; ++it) {
        int nl = it * 4 + rr;
        Wg[(size_t)(i * 512 + n0 + nl) * KG + k0 + c] = (__bf16)tile[c][nl];
    }
}

// generic K x N fp32 -> [N][K] bf16 transpose (tiles of 64x64)
__global__ void transpose_kn(const float* __restrict__ src, __bf16* __restrict__ dst,
                             int K, int N, int srcLS, int dstLS) {
    __shared__ float tile[64][65];
    int i = blockIdx.z;
    int k0 = blockIdx.y * 64, n0 = blockIdx.x * 64;
    int tid = threadIdx.x, c = tid & 63, rr = tid >> 6;
    const float* s = src + (size_t)i * srcLS;
    __bf16* dp = dst + (size_t)i * dstLS;
    for (int it = 0; it < 16; ++it) {
        int kl = it * 4 + rr;
        tile[kl][c] = s[(k0 + kl) * N + n0 + c];
    }
    __syncthreads();
    for (int it = 0; it < 16; ++it) {
        int nl = it * 4 + rr;
        dp[(size_t)(n0 + nl) * K + k0 + c] = (__bf16)tile[c][nl];
    }
}

__global__ void bias_gate_kernel(const float* __restrict__ b_in, const float* __restrict__ b_cond,
                                 float* __restrict__ bias) {
    int idx = blockIdx.x * 256 + threadIdx.x;   // 0..6143
    int i = idx >> 9, np = idx & 511;
    int phys = ((np >> 4) & 1) * 256 + (np >> 5) * 16 + (np & 15);
    bias[idx] = b_in[i * 512 + phys] + b_cond[i * 512 + phys];
}

// wfold[i][k][c] = sum_j w_res_skip[i][k][j] * w_end[j][c]   (i=11 uses w_res_last)
__global__ void wfold_kernel(const float* __restrict__ w_res, const float* __restrict__ w_res_last,
                             const float* __restrict__ w_end, float* __restrict__ wfold) {
    int idx = blockIdx.x * 256 + threadIdx.x;   // 0..24575
    int i = idx >> 11, rem = idx & 2047, k = rem >> 3, c = rem & 7;
    float s = 0.f;
    if (i < 11) {
        const float* wr = w_res + (size_t)(i * 256 + k) * 512 + 256;
        for (int j = 0; j < 256; ++j) s += wr[j] * w_end[j * 8 + c];
    } else {
        const float* wr = w_res_last + k * 256;
        for (int j = 0; j < 256; ++j) s += wr[j] * w_end[j * 8 + c];
    }
    wfold[idx] = s;
}

// outconst[c] = b_end[c] + (sum_i b_res_skip[i] + b_res_last) @ w_end
__global__ void outconst_kernel(const float* __restrict__ b_res, const float* __restrict__ b_res_last,
                                const float* __restrict__ b_end, const float* __restrict__ w_end,
                                float* __restrict__ outconst) {
    __shared__ float red[256][8];
    int j = threadIdx.x;
    float bsum = b_res_last[j];
    for (int i = 0; i < 11; ++i) bsum += b_res[i * 512 + 256 + j];
    for (int c = 0; c < 8; ++c) red[j][c] = bsum * w_end[j * 8 + c];
    __syncthreads();
    if (j < 8) {
        float s = b_end[j];
        for (int t = 0; t < 256; ++t) s += red[t][j];
        outconst[j] = s;
    }
}

__global__ void out_init_kernel(const float* __restrict__ outconst, float* __restrict__ out) {
    int idx = blockIdx.x * 256 + threadIdx.x;
    out[idx] = outconst[idx & 7];
}

// ---------------- main GEMM kernels ----------------

// fused conv + cond + gate. Global->reg->LDS 2-stage pipeline + LDS double-buffer:
// one barrier per k-step; loads for tile k+2 issue during compute of tile k.
// Grid: x = m (fast, 256), y = n (4) so the 4 A-sharing n-blocks land on one XCD.
__global__ __launch_bounds__(256) void gate_kernel(
    const __bf16* __restrict__ started_pad, const __bf16* __restrict__ spect,
    const __bf16* __restrict__ Wg,     // layer base [512][1408]
    const float* __restrict__ bias,    // layer base [512] (interleaved order)
    __bf16* __restrict__ activated, int d) {
    __shared__ __align__(16) __bf16 As[2][128 * 32];
    __shared__ __align__(16) __bf16 Bs[2][128 * 32];
    const int tid = threadIdx.x;
    const int m0 = blockIdx.x * 128;
    const int n0 = blockIdx.y * 128;
    const int padbase = ((m0 >> 12) << 13) + PAD + (m0 & 4095);
    const int srow = tid >> 2;
    const int skq = (tid & 3) * 8;
    const int wave = tid >> 6, lane = tid & 63;
    const int wm = (wave >> 1) * 64, wn = (wave & 1) * 64;
    const int quad = lane >> 4, l15 = lane & 15;

    f32x4 acc[4][4];
    for (int i = 0; i < 4; i++)
        for (int j = 0; j < 4; j++) acc[i][j] = f32x4{0.f, 0.f, 0.f, 0.f};

    const __bf16* Bbase = Wg + (n0 + srow) * KG + skq;

    bf16x8 rA0, rA1, rB0, rB1;
    auto loadTile = [&](int kk) {
        const __bf16* gA0;
        int rstride;
        if (kk < 768) {
            int tap = kk >> 8;
            int koff = kk & 255;
            gA0 = started_pad + (padbase + srow + (tap - 1) * d) * 256 + koff + skq;
            rstride = 256;
        } else {
            gA0 = spect + (m0 + srow) * 640 + (kk - 768) + skq;
            rstride = 640;
        }
        rA0 = *(const bf16x8*)gA0;
        rA1 = *(const bf16x8*)(gA0 + 64 * rstride);
        const __bf16* gB0 = Bbase + kk;
        rB0 = *(const bf16x8*)gB0;
        rB1 = *(const bf16x8*)(gB0 + 64 * KG);
    };

    // prologue: tile 0 -> buf0, tile 1 -> regs
    loadTile(0);
    *(bf16x8*)&As[0][srow * 32 + skq] = rA0;
    *(bf16x8*)&As[0][(64 + srow) * 32 + skq] = rA1;
    *(bf16x8*)&Bs[0][srow * 32 + skq] = rB0;
    *(bf16x8*)&Bs[0][(64 + srow) * 32 + skq] = rB1;
    loadTile(32);
    __syncthreads();

    for (int ks = 0; ks < 44; ++ks) {
        const int cur = ks & 1, nxt = cur ^ 1;
        bf16x8 a[4], b[4];
        for (int mi = 0; mi < 4; mi++) a[mi] = *(const bf16x8*)&As[cur][(wm + mi * 16 + l15) * 32 + quad * 8];
        for (int ni = 0; ni < 4; ni++) b[ni] = *(const bf16x8*)&Bs[cur][(wn + ni * 16 + l15) * 32 + quad * 8];
        if (ks + 1 < 44) {
            *(bf16x8*)&As[nxt][srow * 32 + skq] = rA0;
            *(bf16x8*)&As[nxt][(64 + srow) * 32 + skq] = rA1;
            *(bf16x8*)&Bs[nxt][srow * 32 + skq] = rB0;
            *(bf16x8*)&Bs[nxt][(64 + srow) * 32 + skq] = rB1;
        }
        if (ks + 2 < 44) loadTile((ks + 2) * 32);
        for (int mi = 0; mi < 4; mi++)
            for (int ni = 0; ni < 4; ni++)
                acc[mi][ni] = __builtin_amdgcn_mfma_f32_16x16x32_bf16(a[mi], b[ni], acc[mi][ni], 0, 0, 0);
        __syncthreads();
    }

    // epilogue: gating. n' pairs: (ni even = tanh group, ni odd = sigmoid of same 16 channels)
    int chbase = ((n0 + wn) >> 1) + l15;
    for (int nj = 0; nj < 2; ++nj) {
        int colT = wn + nj * 32 + l15;
        float bt = bias[n0 + colT];
        float bs = bias[n0 + colT + 16];
        int ch = chbase + nj * 16;
        for (int mi = 0; mi < 4; ++mi) {
            for (int reg = 0; reg < 4; ++reg) {
                int r = m0 + wm + mi * 16 + quad * 4 + reg;
                float xt = acc[mi][2 * nj][reg] + bt;
                float xs = acc[mi][2 * nj + 1][reg] + bs;
                float th = 2.f / (1.f + __expf(-2.f * xt)) - 1.f;
                float sg = 1.f / (1.f + __expf(-xs));
                activated[r * 256 + ch] = (__bf16)(th * sg);
            }
        }
    }
}

// rs_res = activated @ Wr + b_res ; started_pad += rs_res (bf16 RMW)
// blocks with n0==0 additionally accumulate out += activated @ wfold (float4 RMW, unique rows)
// L2-hot operands: g2l16 staging (reg-stage pipeline regressed this kernel in R3).
__global__ __launch_bounds__(256) void res_kernel(
    const __bf16* __restrict__ activated, const __bf16* __restrict__ Wr,  // [256][256]
    const float* __restrict__ b_res,      // layer base (first 256 cols used)
    const float* __restrict__ wfold,      // layer base [256][8]
    __bf16* __restrict__ started_pad, float* __restrict__ out) {
    __shared__ __align__(16) __bf16 As[128 * 32];
    __shared__ __align__(16) __bf16 Bs[128 * 32];
    __shared__ __align__(16) float Wf[2048];   // 256 x 8
    const int tid = threadIdx.x;
    const int m0 = blockIdx.y * 128;
    const int n0 = blockIdx.x * 128;
    const int srow = tid >> 2;
    const int skq = (tid & 3) * 8;
    const int wave = tid >> 6, lane = tid & 63;
    const int wm = (wave >> 1) * 64, wn = (wave & 1) * 64;
    const int quad = lane >> 4, l15 = lane & 15;
    const bool doOut = (blockIdx.x == 0);
    const int row2 = tid >> 1, half = tid & 1;

    if (doOut) {
        float4* wf4 = (float4*)Wf;
        const float4* src4 = (const float4*)wfold;
        wf4[tid] = src4[tid];
        wf4[256 + tid] = src4[256 + tid];
    }

    f32x4 acc[4][4];
    for (int i = 0; i < 4; i++)
        for (int j = 0; j < 4; j++) acc[i][j] = f32x4{0.f, 0.f, 0.f, 0.f};
    float ox = 0.f, oy = 0.f, oz = 0.f, ow = 0.f;

    const __bf16* Abase = activated + (m0 + srow) * 256 + skq;
    const __bf16* Bbase = Wr + (n0 + srow) * 256 + skq;

    for (int ks = 0; ks < 8; ++ks) {
        int kk = ks * 32;
        g2l16(Abase + kk, &As[srow * 32 + skq]);
        g2l16(Abase + kk + 64 * 256, &As[(64 + srow) * 32 + skq]);
        g2l16(Bbase + kk, &Bs[srow * 32 + skq]);
        g2l16(Bbase + kk + 64 * 256, &Bs[(64 + srow) * 32 + skq]);
        __syncthreads();
        bf16x8 a[4], b[4];
        for (int mi = 0; mi < 4; mi++) a[mi] = *(const bf16x8*)&As[(wm + mi * 16 + l15) * 32 + quad * 8];
        for (int ni = 0; ni < 4; ni++) b[ni] = *(const bf16x8*)&Bs[(wn + ni * 16 + l15) * 32 + quad * 8];
        for (int mi = 0; mi < 4; mi++)
            for (int ni = 0; ni < 4; ni++)
                acc[mi][ni] = __builtin_amdgcn_mfma_f32_16x16x32_bf16(a[mi], b[ni], acc[mi][ni], 0, 0, 0);
        if (doOut) {
            const bf16x8* ap = (const bf16x8*)&As[row2 * 32];
            const float4* wf = (const float4*)Wf;
            for (int c8 = 0; c8 < 4; ++c8) {
                bf16x8 av = ap[c8];
                int kb = (kk + c8 * 8) * 2 + half;
                for (int e = 0; e < 8; ++e) {
                    float a = (float)av[e];
                    float4 w = wf[kb + e * 2];
                    ox += a * w.x; oy += a * w.y; oz += a * w.z; ow += a * w.w;
                }
            }
        }
        __syncthreads();
    }

    for (int ni = 0; ni < 4; ++ni) {
        int col = n0 + wn + ni * 16 + l15;
        float bcol = b_res[col];
        for (int mi = 0; mi < 4; ++mi) {
            for (int reg = 0; reg < 4; ++reg) {
                int r = m0 + wm + mi * 16 + quad * 4 + reg;
                int pr = ((r >> 12) << 13) + PAD + (r & 4095);
                int idx = pr * 256 + col;
                float f = (float)started_pad[idx] + acc[mi][ni][reg] + bcol;
                started_pad[idx] = (__bf16)f;
            }
        }
    }
    if (doOut) {
        int r = m0 + row2;
        float4* op = (float4*)&out[r * 8 + half * 4];
        float4 o = *op;
        o.x += ox; o.y += oy; o.z += oz; o.w += ow;
        *op = o;
    }
}

// last layer: out += activated @ wfold[11]  (no res half)
__global__ __launch_bounds__(256) void outacc_kernel(
    const __bf16* __restrict__ activated, const float* __restrict__ wfold,
    float* __restrict__ out) {
    __shared__ __align__(16) float Wf[2048];
    int tid = threadIdx.x;
    ((float4*)Wf)[tid] = ((const float4*)wfold)[tid];
    ((float4*)Wf)[256 + tid] = ((const float4*)wfold)[256 + tid];
    __syncthreads();
    int row2 = tid >> 1, half = tid & 1;
    int r = blockIdx.x * 128 + row2;
    const bf16x8* ap = (const bf16x8*)(activated + r * 256);
    const float4* wf = (const float4*)Wf;
    float ox = 0.f, oy = 0.f, oz = 0.f, ow = 0.f;
    for (int c8 = 0; c8 < 32; ++c8) {
        bf16x8 av = ap[c8];
        for (int e = 0; e < 8; ++e) {
            float a = (float)av[e];
            float4 w = wf[(c8 * 8 + e) * 2 + half];
            ox += a * w.x; oy += a * w.y; oz += a * w.z; ow += a * w.w;
        }
    }
    float4* op = (float4*)&out[r * 8 + half * 4];
    float4 o = *op;
    o.x += ox; o.y += oy; o.z += oz; o.w += ow;
    *op = o;
}

// ---------------- launch ----------------

extern "C" void kernel_launch(void* const* d_in, const int* in_sizes, int n_in,
                              void* d_out, int out_size, void* d_ws, size_t ws_size,
                              hipStream_t stream) {
    const float* audio      = (const float*)d_in[0];
    const float* spect      = (const float*)d_in[1];
    const float* w_start    = (const float*)d_in[2];
    const float* b_start    = (const float*)d_in[3];
    const float* w_in       = (const float*)d_in[4];
    const float* b_in       = (const float*)d_in[5];
    const float* w_cond     = (const float*)d_in[6];
    const float* b_cond     = (const float*)d_in[7];
    const float* w_res      = (const float*)d_in[8];
    const float* b_res      = (const float*)d_in[9];
    const float* w_res_last = (const float*)d_in[10];
    const float* b_res_last = (const float*)d_in[11];
    const float* w_end      = (const float*)d_in[12];
    const float* b_end      = (const float*)d_in[13];
    float* out = (float*)d_out;

    char* ws = (char*)d_ws;
    __bf16* started_pad = (__bf16*)ws; ws += 33554432;   // 65536 x 256 bf16 (padded)
    __bf16* activated   = (__bf16*)ws; ws += 16777216;   // 32768 x 256 bf16
    __bf16* spect_bf    = (__bf16*)ws; ws += 41943040;   // 32768 x 640 bf16
    __bf16* Wg          = (__bf16*)ws; ws += 17301504;   // 12 x 512 x 1408 bf16
    __bf16* Wr          = (__bf16*)ws; ws += 1441792;    // 11 x 256 x 256 bf16 (res half, [n][k])
    float*  wfold       = (float*)ws;  ws += 98304;      // 12 x 256 x 8 f32
    float*  biasg       = (float*)ws;  ws += 24576;      // 12 x 512 f32
    float*  outconst    = (float*)ws;  ws += 256;        // 8 f32

    zero_kernel<<<dim3(8192), 256, 0, stream>>>((uint4*)started_pad);
    cvt_bf16_kernel<<<dim3(81920), 256, 0, stream>>>(spect, spect_bf, 20971520);
    transpose_gate<<<dim3(8, 22, 12), 256, 0, stream>>>(w_in, w_cond, Wg);
    transpose_kn<<<dim3(4, 4, 11), 256, 0, stream>>>(w_res, Wr, 256, 512, 256 * 512, 256 * 256);
    bias_gate_kernel<<<dim3(24), 256, 0, stream>>>(b_in, b_cond, biasg);
    wfold_kernel<<<dim3(96), 256, 0, stream>>>(w_res, w_res_last, w_end, wfold);
    outconst_kernel<<<dim3(1), 256, 0, stream>>>(b_res, b_res_last, b_end, w_end, outconst);
    out_init_kernel<<<dim3(1024), 256, 0, stream>>>(outconst, out);
    start_kernel<<<dim3(32768), 256, 0, stream>>>(audio, w_start, b_start, started_pad);

    for (int i = 0; i < 12; ++i) {
        gate_kernel<<<dim3(256, 4), 256, 0, stream>>>(
            started_pad, spect_bf, Wg + (size_t)i * 512 * KG, biasg + i * 512, activated, 1 << i);
        if (i < 11) {
            res_kernel<<<dim3(2, 256), 256, 0, stream>>>(
                activated, Wr + (size_t)i * 256 * 256, b_res + i * 512,
                wfold + i * 2048, started_pad, out);
        } else {
            outacc_kernel<<<dim3(256), 256, 0, stream>>>(activated, wfold + 11 * 2048, out);
        }
    }
}

// Round 5
// 1256.245 us; speedup vs baseline: 1.5548x; 1.0576x over previous
//
#include <hip/hip_runtime.h>
#include <cstdint>

#define PAD 2048
#define KG 1408   // 3*256 conv + 640 cond
#define LDW 36    // padded LDS row stride (elements); 18 words -> conflict-free-ish

typedef float f32x4 __attribute__((ext_vector_type(4)));
typedef __bf16 bf16x8 __attribute__((ext_vector_type(8)));

__device__ __forceinline__ void g2l16(const void* g, void* l) {
    __builtin_amdgcn_global_load_lds(
        (__attribute__((address_space(1))) void*)(uintptr_t)g,
        (__attribute__((address_space(3))) void*)(uint32_t)(uintptr_t)l,
        16, 0, 0);
}

// ---------------- setup kernels ----------------

__global__ void cvt_bf16_kernel(const float* __restrict__ src, __bf16* __restrict__ dst, int n) {
    int idx = blockIdx.x * 256 + threadIdx.x;
    if (idx < n) dst[idx] = (__bf16)src[idx];
}

// whole padded started buffer: pad rows = 0, data rows = audio @ w_start + b_start
__global__ void init_started_kernel(const float* __restrict__ audio, const float* __restrict__ w_start,
                                    const float* __restrict__ b_start, __bf16* __restrict__ started_pad) {
    int pr = blockIdx.x, c = threadIdx.x;
    int off = pr & 8191;
    float s = 0.f;
    if (off >= PAD && off < PAD + 4096) {
        int r = ((pr >> 13) << 12) + (off - PAD);
        float a0 = audio[r * 4 + 0], a1 = audio[r * 4 + 1], a2 = audio[r * 4 + 2], a3 = audio[r * 4 + 3];
        s = b_start[c] + a0 * w_start[c] + a1 * w_start[256 + c] + a2 * w_start[512 + c] + a3 * w_start[768 + c];
    }
    started_pad[(size_t)pr * 256 + c] = (__bf16)s;
}

// Build Wg[i][n'][k] bf16 (n' interleaved by 16: tanh16/sig16 groups), k: 0-767 conv taps, 768-1407 cond
__global__ void transpose_gate(const float* __restrict__ w_in, const float* __restrict__ w_cond,
                               __bf16* __restrict__ Wg) {
    __shared__ float tile[64][65];
    int i = blockIdx.z;
    int k0 = blockIdx.y * 64, n0 = blockIdx.x * 64;
    int tid = threadIdx.x, c = tid & 63, rr = tid >> 6;
    for (int it = 0; it < 16; ++it) {
        int kl = it * 4 + rr;
        int k = k0 + kl;
        int np = n0 + c;
        int phys = ((np >> 4) & 1) * 256 + (np >> 5) * 16 + (np & 15);
        float v;
        if (k < 768) v = w_in[((i * 3 + (k >> 8)) * 256 + (k & 255)) * 512 + phys];
        else         v = w_cond[(i * 640 + (k - 768)) * 512 + phys];
        tile[kl][c] = v;
    }
    __syncthreads();
    for (int it = 0; it < 16; ++it) {
        int nl = it * 4 + rr;
        Wg[(size_t)(i * 512 + n0 + nl) * KG + k0 + c] = (__bf16)tile[c][nl];
    }
}

// generic K x N fp32 -> [N][K] bf16 transpose (tiles of 64x64)
__global__ void transpose_kn(const float* __restrict__ src, __bf16* __restrict__ dst,
                             int K, int N, int srcLS, int dstLS) {
    __shared__ float tile[64][65];
    int i = blockIdx.z;
    int k0 = blockIdx.y * 64, n0 = blockIdx.x * 64;
    int tid = threadIdx.x, c = tid & 63, rr = tid >> 6;
    const float* s = src + (size_t)i * srcLS;
    __bf16* dp = dst + (size_t)i * dstLS;
    for (int it = 0; it < 16; ++it) {
        int kl = it * 4 + rr;
        tile[kl][c] = s[(k0 + kl) * N + n0 + c];
    }
    __syncthreads();
    for (int it = 0; it < 16; ++it) {
        int nl = it * 4 + rr;
        dp[(size_t)(n0 + nl) * K + k0 + c] = (__bf16)tile[c][nl];
    }
}

__global__ void bias_gate_kernel(const float* __restrict__ b_in, const float* __restrict__ b_cond,
                                 float* __restrict__ bias) {
    int idx = blockIdx.x * 256 + threadIdx.x;   // 0..6143
    int i = idx >> 9, np = idx & 511;
    int phys = ((np >> 4) & 1) * 256 + (np >> 5) * 16 + (np & 15);
    bias[idx] = b_in[i * 512 + phys] + b_cond[i * 512 + phys];
}

// blocks 0..95: wfold[i][k][c] = sum_j w_res_skip[i][k][j] * w_end[j][c]  (i=11 uses w_res_last)
// block 96: outconst[c] = b_end[c] + (sum_i b_res_skip[i] + b_res_last) @ w_end
__global__ void wfold_kernel(const float* __restrict__ w_res, const float* __restrict__ w_res_last,
                             const float* __restrict__ w_end, const float* __restrict__ b_res,
                             const float* __restrict__ b_res_last, const float* __restrict__ b_end,
                             float* __restrict__ wfold, float* __restrict__ outconst) {
    if (blockIdx.x == 96) {
        __shared__ float red[256][8];
        int j = threadIdx.x;
        float bsum = b_res_last[j];
        for (int i = 0; i < 11; ++i) bsum += b_res[i * 512 + 256 + j];
        for (int c = 0; c < 8; ++c) red[j][c] = bsum * w_end[j * 8 + c];
        __syncthreads();
        if (j < 8) {
            float s = b_end[j];
            for (int t = 0; t < 256; ++t) s += red[t][j];
            outconst[j] = s;
        }
        return;
    }
    int idx = blockIdx.x * 256 + threadIdx.x;   // 0..24575
    int i = idx >> 11, rem = idx & 2047, k = rem >> 3, c = rem & 7;
    float s = 0.f;
    if (i < 11) {
        const float* wr = w_res + (size_t)(i * 256 + k) * 512 + 256;
        for (int j = 0; j < 256; ++j) s += wr[j] * w_end[j * 8 + c];
    } else {
        const float* wr = w_res_last + k * 256;
        for (int j = 0; j < 256; ++j) s += wr[j] * w_end[j * 8 + c];
    }
    wfold[idx] = s;
}

// ---------------- main GEMM kernels ----------------

// fused conv + cond + gate. LDS double-buffer (1 barrier/step), padded rows (LDW),
// 3-step register prefetch (two reg sets, manual unroll-2).
// Grid: x = m (fast, 256), y = n (4) so the 4 A-sharing n-blocks land on one XCD.
__global__ __launch_bounds__(256) void gate_kernel(
    const __bf16* __restrict__ started_pad, const __bf16* __restrict__ spect,
    const __bf16* __restrict__ Wg,     // layer base [512][1408]
    const float* __restrict__ bias,    // layer base [512] (interleaved order)
    __bf16* __restrict__ activated, int d) {
    __shared__ __align__(16) __bf16 As[2][128 * LDW];
    __shared__ __align__(16) __bf16 Bs[2][128 * LDW];
    const int tid = threadIdx.x;
    const int m0 = blockIdx.x * 128;
    const int n0 = blockIdx.y * 128;
    const int padbase = ((m0 >> 12) << 13) + PAD + (m0 & 4095);
    const int srow = tid >> 2;
    const int skq = (tid & 3) * 8;
    const int wave = tid >> 6, lane = tid & 63;
    const int wm = (wave >> 1) * 64, wn = (wave & 1) * 64;
    const int quad = lane >> 4, l15 = lane & 15;

    f32x4 acc[4][4];
    for (int i = 0; i < 4; i++)
        for (int j = 0; j < 4; j++) acc[i][j] = f32x4{0.f, 0.f, 0.f, 0.f};

    const __bf16* Bbase = Wg + (n0 + srow) * KG + skq;

    auto loadTile = [&](int kk, bf16x8& sA0, bf16x8& sA1, bf16x8& sB0, bf16x8& sB1) {
        const __bf16* gA0;
        int rstride;
        if (kk < 768) {
            int tap = kk >> 8;
            int koff = kk & 255;
            gA0 = started_pad + (padbase + srow + (tap - 1) * d) * 256 + koff + skq;
            rstride = 256;
        } else {
            gA0 = spect + (m0 + srow) * 640 + (kk - 768) + skq;
            rstride = 640;
        }
        sA0 = *(const bf16x8*)gA0;
        sA1 = *(const bf16x8*)(gA0 + 64 * rstride);
        const __bf16* gB0 = Bbase + kk;
        sB0 = *(const bf16x8*)gB0;
        sB1 = *(const bf16x8*)(gB0 + 64 * KG);
    };

    bf16x8 aA0, aA1, aB0, aB1;   // set 0
    bf16x8 bA0, bA1, bB0, bB1;   // set 1

    // prologue: tile0 -> buf0 (via set0); tile1 -> set0; tile2 -> set1
    loadTile(0, aA0, aA1, aB0, aB1);
    *(bf16x8*)&As[0][srow * LDW + skq] = aA0;
    *(bf16x8*)&As[0][(64 + srow) * LDW + skq] = aA1;
    *(bf16x8*)&Bs[0][srow * LDW + skq] = aB0;
    *(bf16x8*)&Bs[0][(64 + srow) * LDW + skq] = aB1;
    loadTile(32, aA0, aA1, aB0, aB1);
    loadTile(64, bA0, bA1, bB0, bB1);
    __syncthreads();

    auto step = [&](int ks, int cur, bf16x8& sA0, bf16x8& sA1, bf16x8& sB0, bf16x8& sB1) {
        const int nxt = cur ^ 1;
        bf16x8 a[4], b[4];
        for (int mi = 0; mi < 4; mi++) a[mi] = *(const bf16x8*)&As[cur][(wm + mi * 16 + l15) * LDW + quad * 8];
        for (int ni = 0; ni < 4; ni++) b[ni] = *(const bf16x8*)&Bs[cur][(wn + ni * 16 + l15) * LDW + quad * 8];
        if (ks + 1 < 44) {
            *(bf16x8*)&As[nxt][srow * LDW + skq] = sA0;
            *(bf16x8*)&As[nxt][(64 + srow) * LDW + skq] = sA1;
            *(bf16x8*)&Bs[nxt][srow * LDW + skq] = sB0;
            *(bf16x8*)&Bs[nxt][(64 + srow) * LDW + skq] = sB1;
        }
        if (ks + 3 < 44) loadTile((ks + 3) * 32, sA0, sA1, sB0, sB1);
        for (int mi = 0; mi < 4; mi++)
            for (int ni = 0; ni < 4; ni++)
                acc[mi][ni] = __builtin_amdgcn_mfma_f32_16x16x32_bf16(a[mi], b[ni], acc[mi][ni], 0, 0, 0);
        __syncthreads();
    };

    for (int ks = 0; ks < 44; ks += 2) {
        step(ks,     0, aA0, aA1, aB0, aB1);
        step(ks + 1, 1, bA0, bA1, bB0, bB1);
    }

    // epilogue: gating. n' pairs: (ni even = tanh group, ni odd = sigmoid of same 16 channels)
    int chbase = ((n0 + wn) >> 1) + l15;
    for (int nj = 0; nj < 2; ++nj) {
        int colT = wn + nj * 32 + l15;
        float bt = bias[n0 + colT];
        float bs = bias[n0 + colT + 16];
        int ch = chbase + nj * 16;
        for (int mi = 0; mi < 4; ++mi) {
            for (int reg = 0; reg < 4; ++reg) {
                int r = m0 + wm + mi * 16 + quad * 4 + reg;
                float xt = acc[mi][2 * nj][reg] + bt;
                float xs = acc[mi][2 * nj + 1][reg] + bs;
                float th = 2.f / (1.f + __expf(-2.f * xt)) - 1.f;
                float sg = 1.f / (1.f + __expf(-xs));
                activated[r * 256 + ch] = (__bf16)(th * sg);
            }
        }
    }
}

// rs_res = activated @ Wr + b_res ; started_pad += rs_res (bf16 RMW)
// Grid (256,2): x = m (fast) so the reader of m-tile x sits on the XCD that produced it.
// Blocks with blockIdx.y==0 also accumulate out += activated @ wfold (init on layer 0).
__global__ __launch_bounds__(256) void res_kernel(
    const __bf16* __restrict__ activated, const __bf16* __restrict__ Wr,  // [256][256]
    const float* __restrict__ b_res,      // layer base (first 256 cols used)
    const float* __restrict__ wfold,      // layer base [256][8]
    const float* __restrict__ outconst,
    __bf16* __restrict__ started_pad, float* __restrict__ out, int initOut) {
    __shared__ __align__(16) __bf16 As[128 * 32];
    __shared__ __align__(16) __bf16 Bs[128 * 32];
    __shared__ __align__(16) float Wf[2048];   // 256 x 8
    const int tid = threadIdx.x;
    const int m0 = blockIdx.x * 128;
    const int n0 = blockIdx.y * 128;
    const int srow = tid >> 2;
    const int skq = (tid & 3) * 8;
    const int wave = tid >> 6, lane = tid & 63;
    const int wm = (wave >> 1) * 64, wn = (wave & 1) * 64;
    const int quad = lane >> 4, l15 = lane & 15;
    const bool doOut = (blockIdx.y == 0);
    const int row2 = tid >> 1, half = tid & 1;

    if (doOut) {
        float4* wf4 = (float4*)Wf;
        const float4* src4 = (const float4*)wfold;
        wf4[tid] = src4[tid];
        wf4[256 + tid] = src4[256 + tid];
    }

    f32x4 acc[4][4];
    for (int i = 0; i < 4; i++)
        for (int j = 0; j < 4; j++) acc[i][j] = f32x4{0.f, 0.f, 0.f, 0.f};
    float ox = 0.f, oy = 0.f, oz = 0.f, ow = 0.f;

    const __bf16* Abase = activated + (m0 + srow) * 256 + skq;
    const __bf16* Bbase = Wr + (n0 + srow) * 256 + skq;

    for (int ks = 0; ks < 8; ++ks) {
        int kk = ks * 32;
        g2l16(Abase + kk, &As[srow * 32 + skq]);
        g2l16(Abase + kk + 64 * 256, &As[(64 + srow) * 32 + skq]);
        g2l16(Bbase + kk, &Bs[srow * 32 + skq]);
        g2l16(Bbase + kk + 64 * 256, &Bs[(64 + srow) * 32 + skq]);
        __syncthreads();
        bf16x8 a[4], b[4];
        for (int mi = 0; mi < 4; mi++) a[mi] = *(const bf16x8*)&As[(wm + mi * 16 + l15) * 32 + quad * 8];
        for (int ni = 0; ni < 4; ni++) b[ni] = *(const bf16x8*)&Bs[(wn + ni * 16 + l15) * 32 + quad * 8];
        for (int mi = 0; mi < 4; mi++)
            for (int ni = 0; ni < 4; ni++)
                acc[mi][ni] = __builtin_amdgcn_mfma_f32_16x16x32_bf16(a[mi], b[ni], acc[mi][ni], 0, 0, 0);
        if (doOut) {
            const bf16x8* ap = (const bf16x8*)&As[row2 * 32];
            const float4* wf = (const float4*)Wf;
            for (int c8 = 0; c8 < 4; ++c8) {
                bf16x8 av = ap[c8];
                int kb = (kk + c8 * 8) * 2 + half;
                for (int e = 0; e < 8; ++e) {
                    float a = (float)av[e];
                    float4 w = wf[kb + e * 2];
                    ox += a * w.x; oy += a * w.y; oz += a * w.z; ow += a * w.w;
                }
            }
        }
        __syncthreads();
    }

    for (int ni = 0; ni < 4; ++ni) {
        int col = n0 + wn + ni * 16 + l15;
        float bcol = b_res[col];
        for (int mi = 0; mi < 4; ++mi) {
            for (int reg = 0; reg < 4; ++reg) {
                int r = m0 + wm + mi * 16 + quad * 4 + reg;
                int pr = ((r >> 12) << 13) + PAD + (r & 4095);
                int idx = pr * 256 + col;
                float f = (float)started_pad[idx] + acc[mi][ni][reg] + bcol;
                started_pad[idx] = (__bf16)f;
            }
        }
    }
    if (doOut) {
        int r = m0 + row2;
        float4* op = (float4*)&out[r * 8 + half * 4];
        float4 o;
        if (initOut) {
            float4 oc = ((const float4*)outconst)[half];
            o.x = oc.x + ox; o.y = oc.y + oy; o.z = oc.z + oz; o.w = oc.w + ow;
        } else {
            o = *op;
            o.x += ox; o.y += oy; o.z += oz; o.w += ow;
        }
        *op = o;
    }
}

// last layer: out += activated @ wfold[11]  (no res half). Grid x = m (XCD-aligned).
__global__ __launch_bounds__(256) void outacc_kernel(
    const __bf16* __restrict__ activated, const float* __restrict__ wfold,
    float* __restrict__ out) {
    __shared__ __align__(16) float Wf[2048];
    int tid = threadIdx.x;
    ((float4*)Wf)[tid] = ((const float4*)wfold)[tid];
    ((float4*)Wf)[256 + tid] = ((const float4*)wfold)[256 + tid];
    __syncthreads();
    int row2 = tid >> 1, half = tid & 1;
    int r = blockIdx.x * 128 + row2;
    const bf16x8* ap = (const bf16x8*)(activated + r * 256);
    const float4* wf = (const float4*)Wf;
    float ox = 0.f, oy = 0.f, oz = 0.f, ow = 0.f;
    for (int c8 = 0; c8 < 32; ++c8) {
        bf16x8 av = ap[c8];
        for (int e = 0; e < 8; ++e) {
            float a = (float)av[e];
            float4 w = wf[(c8 * 8 + e) * 2 + half];
            ox += a * w.x; oy += a * w.y; oz += a * w.z; ow += a * w.w;
        }
    }
    float4* op = (float4*)&out[r * 8 + half * 4];
    float4 o = *op;
    o.x += ox; o.y += oy; o.z += oz; o.w += ow;
    *op = o;
}

// ---------------- launch ----------------

extern "C" void kernel_launch(void* const* d_in, const int* in_sizes, int n_in,
                              void* d_out, int out_size, void* d_ws, size_t ws_size,
                              hipStream_t stream) {
    const float* audio      = (const float*)d_in[0];
    const float* spect      = (const float*)d_in[1];
    const float* w_start    = (const float*)d_in[2];
    const float* b_start    = (const float*)d_in[3];
    const float* w_in       = (const float*)d_in[4];
    const float* b_in       = (const float*)d_in[5];
    const float* w_cond     = (const float*)d_in[6];
    const float* b_cond     = (const float*)d_in[7];
    const float* w_res      = (const float*)d_in[8];
    const float* b_res      = (const float*)d_in[9];
    const float* w_res_last = (const float*)d_in[10];
    const float* b_res_last = (const float*)d_in[11];
    const float* w_end      = (const float*)d_in[12];
    const float* b_end      = (const float*)d_in[13];
    float* out = (float*)d_out;

    char* ws = (char*)d_ws;
    __bf16* started_pad = (__bf16*)ws; ws += 33554432;   // 65536 x 256 bf16 (padded)
    __bf16* activated   = (__bf16*)ws; ws += 16777216;   // 32768 x 256 bf16
    __bf16* spect_bf    = (__bf16*)ws; ws += 41943040;   // 32768 x 640 bf16
    __bf16* Wg          = (__bf16*)ws; ws += 17301504;   // 12 x 512 x 1408 bf16
    __bf16* Wr          = (__bf16*)ws; ws += 1441792;    // 11 x 256 x 256 bf16 (res half, [n][k])
    float*  wfold       = (float*)ws;  ws += 98304;      // 12 x 256 x 8 f32
    float*  biasg       = (float*)ws;  ws += 24576;      // 12 x 512 f32
    float*  outconst    = (float*)ws;  ws += 256;        // 8 f32

    init_started_kernel<<<dim3(65536), 256, 0, stream>>>(audio, w_start, b_start, started_pad);
    cvt_bf16_kernel<<<dim3(81920), 256, 0, stream>>>(spect, spect_bf, 20971520);
    transpose_gate<<<dim3(8, 22, 12), 256, 0, stream>>>(w_in, w_cond, Wg);
    transpose_kn<<<dim3(4, 4, 11), 256, 0, stream>>>(w_res, Wr, 256, 512, 256 * 512, 256 * 256);
    bias_gate_kernel<<<dim3(24), 256, 0, stream>>>(b_in, b_cond, biasg);
    wfold_kernel<<<dim3(97), 256, 0, stream>>>(w_res, w_res_last, w_end, b_res, b_res_last, b_end,
                                               wfold, outconst);

    for (int i = 0; i < 12; ++i) {
        gate_kernel<<<dim3(256, 4), 256, 0, stream>>>(
            started_pad, spect_bf, Wg + (size_t)i * 512 * KG, biasg + i * 512, activated, 1 << i);
        if (i < 11) {
            res_kernel<<<dim3(256, 2), 256, 0, stream>>>(
                activated, Wr + (size_t)i * 256 * 256, b_res + i * 512,
                wfold + i * 2048, outconst, started_pad, out, i == 0 ? 1 : 0);
        } else {
            outacc_kernel<<<dim3(256), 256, 0, stream>>>(activated, wfold + 11 * 2048, out);
        }
    }
}